// Round 8
// baseline (492.375 us; speedup 1.0000x reference)
//
#include <hip/hip_runtime.h>
#include <hip/hip_bf16.h>

#define B_   4
#define H_   16
#define LQ   1024
#define LK   2048
#define D_   1024
#define DH   64

typedef __attribute__((ext_vector_type(8))) short  short8;
typedef __attribute__((ext_vector_type(4))) float  float4_;
typedef __attribute__((ext_vector_type(4))) unsigned int uint4_;

static __device__ __forceinline__ float bf2f(unsigned short u) {
    unsigned int x = ((unsigned int)u) << 16;
    return __builtin_bit_cast(float, x);
}
static __device__ __forceinline__ unsigned short f2bf(float f) {
    unsigned int x = __builtin_bit_cast(unsigned int, f);
    unsigned int lsb = (x >> 16) & 1u;
    x += 0x7fffu + lsb;
    return (unsigned short)(x >> 16);
}
// packed RNE fp32x2 -> bf16x2 (v_cvt_pk_bf16_f32 on gfx950)
static __device__ __forceinline__ unsigned int pack2(float a, float b) {
    __hip_bfloat162 h = __float22bfloat162_rn(make_float2(a, b));
    unsigned int r;
    __builtin_memcpy(&r, &h, 4);
    return r;
}
// DPP lane-permute within 16-lane rows (VALU pipe). 0xB1=xor1, 0x4E=xor2,
// 0x141=row_half_mirror, 0x140=row_mirror.
template<int CTRL>
static __device__ __forceinline__ float dppmv(float x) {
    int i = __builtin_bit_cast(int, x);
    int r = __builtin_amdgcn_update_dpp(i, i, CTRL, 0xf, 0xf, false);
    return __builtin_bit_cast(float, r);
}

#define MFMA(a, b, c) __builtin_amdgcn_mfma_f32_16x16x32_bf16((a), (b), (c), 0, 0, 0)

// async global->LDS, 16B per lane; LDS dest is wave-uniform base + lane*16.
#define GLOAD_LDS16(g, l) __builtin_amdgcn_global_load_lds( \
    (const __attribute__((address_space(1))) unsigned int*)(const void*)(g), \
    (__attribute__((address_space(3))) unsigned int*)(void*)(l), 16, 0, 0)

// ---------------------------------------------------------------------------
// One-shot fp32 -> bf16 conversion: Wq/Wk/Wv, dist_emb, Xq/Xk.
// ---------------------------------------------------------------------------
__global__ __launch_bounds__(256) void conv_kernel(
    const float* __restrict__ Wq, const float* __restrict__ Wk,
    const float* __restrict__ Wv, const float* __restrict__ Eg,
    const float* __restrict__ Xq, const float* __restrict__ Xk,
    unsigned short* __restrict__ cWq, unsigned short* __restrict__ cWk,
    unsigned short* __restrict__ cWv, unsigned short* __restrict__ cEb,
    unsigned short* __restrict__ cXq, unsigned short* __restrict__ cXk)
{
    int bid = blockIdx.x;
    const float* src; unsigned short* dst; int nch;
    if (bid < 512)       { src = Wq; dst = cWq;              nch = 131072;  }
    else if (bid < 1024) { src = Wk; dst = cWk; bid -= 512;  nch = 131072;  }
    else if (bid < 1536) { src = Wv; dst = cWv; bid -= 1024; nch = 131072;  }
    else if (bid < 1664) { src = Eg; dst = cEb; bid -= 1536; nch = 32760;   }
    else if (bid < 3712) { src = Xq; dst = cXq; bid -= 1664; nch = 524288;  }
    else                 { src = Xk; dst = cXk; bid -= 3712; nch = 1048576; }
    int ch = bid * 256 + threadIdx.x;
    if (ch >= nch) return;
    const float* s = src + (size_t)ch * 8;
    float4_ v0 = *(const float4_*)s, v1 = *(const float4_*)(s + 4);
    uint4_ o;
    o[0] = pack2(v0[0], v0[1]); o[1] = pack2(v0[2], v0[3]);
    o[2] = pack2(v1[0], v1[1]); o[3] = pack2(v1[2], v1[3]);
    *(uint4_*)(dst + (size_t)ch * 8) = o;
}

// ---------------------------------------------------------------------------
// Projection GEMM (round-4 config, measured best): pure-bf16 gll GEMM, BK=64,
// LDS double-buffer, stage(next) before compute(cur), one barrier per K-step.
// which 0: Q -> Qh ; 1: K -> Kh ; 2: V -> VT (transposed via LDS).
// ---------------------------------------------------------------------------
__global__ __launch_bounds__(256) void proj_kernel(
    const unsigned short* __restrict__ Xq, const unsigned short* __restrict__ Xk,
    const unsigned short* __restrict__ Wq, const float* __restrict__ bq,
    const unsigned short* __restrict__ Wk, const float* __restrict__ bk,
    const unsigned short* __restrict__ Wv, const float* __restrict__ bv,
    unsigned short* __restrict__ Qh, unsigned short* __restrict__ Kh,
    unsigned short* __restrict__ VT)
{
    __shared__ short smem[32768];      // 65536 B -> 2 blocks/CU
    short* A0 = smem;                  // 128 x 64 bf16
    short* B0 = smem + 8192;
    short* A1 = smem + 16384;
    short* B1 = smem + 24576;
    short* Cs = smem;                  // 128 x 136 (V transpose, aliases)

    int bid = blockIdx.x;
    int which, tm, tn;
    const unsigned short *X; const float* bias; const unsigned short* W;
    if (bid < 256)      { which = 0; int t = bid;       tm = t >> 3; tn = t & 7; X = Xq; W = Wq; bias = bq; }
    else if (bid < 768) { which = 1; int t = bid - 256; tm = t >> 3; tn = t & 7; X = Xk; W = Wk; bias = bk; }
    else                { which = 2; int t = bid - 768; tm = t >> 3; tn = t & 7; X = Xk; W = Wv; bias = bv; }

    int tid  = threadIdx.x;
    int wave = tid >> 6, lane = tid & 63;
    int wr = (wave >> 1) * 64, wc = (wave & 1) * 64;
    int m0 = tm * 128, n0 = tn * 128;

    float4_ acc[4][4];
    for (int a = 0; a < 4; ++a) for (int c = 0; c < 4; ++c) acc[a][c] = (float4_)0.0f;

    int rl = lane >> 3;
    int chs = (lane & 7) ^ rl;
    const unsigned short* Asrc = X + (size_t)(m0 + wave * 32 + rl) * D_ + (chs << 3);
    const unsigned short* Bsrc = W + (size_t)(n0 + wave * 32 + rl) * D_ + (chs << 3);

    int lrow = lane & 15, lk8 = (lane >> 4) * 8;
    int swz = lane & 7;                 // == row&7 for all frag-read rows

    auto stage = [&](short* Ad, short* Bd, int kt) {
        int k0 = kt * 64;
        #pragma unroll
        for (int c = 0; c < 4; ++c) {
            GLOAD_LDS16(Asrc + (size_t)(c * 8) * D_ + k0, &Ad[(wave * 32 + c * 8) * 64]);
            GLOAD_LDS16(Bsrc + (size_t)(c * 8) * D_ + k0, &Bd[(wave * 32 + c * 8) * 64]);
        }
    };
    auto compute = [&](const short* Aa, const short* Bb) {
        #pragma unroll
        for (int kk = 0; kk < 64; kk += 32) {
            int cgrp = (kk + lk8) >> 3;             // logical 16B chunk
            int coff = ((cgrp ^ swz) << 3);         // swizzled elem offset
            short8 af[4], bfr[4];
            #pragma unroll
            for (int rt = 0; rt < 4; ++rt)
                af[rt]  = *(const short8*)(&Aa[(wr + rt * 16 + lrow) * 64 + coff]);
            #pragma unroll
            for (int ct = 0; ct < 4; ++ct)
                bfr[ct] = *(const short8*)(&Bb[(wc + ct * 16 + lrow) * 64 + coff]);
            #pragma unroll
            for (int rt = 0; rt < 4; ++rt)
                #pragma unroll
                for (int ct = 0; ct < 4; ++ct)
                    acc[rt][ct] = MFMA(af[rt], bfr[ct], acc[rt][ct]);
        }
    };

    stage(A0, B0, 0);
    __syncthreads();                   // buf0 staged (barrier drains vmcnt)
    for (int kt = 0; kt < 16; kt += 2) {
        if (kt + 1 < 16) stage(A1, B1, kt + 1);   // loads fly during compute
        compute(A0, B0);
        __syncthreads();               // kt+1 staged; A0/B0 readers done
        if (kt + 2 < 16) stage(A0, B0, kt + 2);
        compute(A1, B1);
        __syncthreads();               // kt+2 staged; A1/B1 readers done
    }
    // last barrier above also protects the Cs alias below.

    int lrow4 = (lane >> 4) * 4, lcol = lane & 15;
    if (which < 2) {
        int lsh = (which == 0) ? 10 : 11;          // LQ=1024, LK=2048
        int Lm1 = (1 << lsh) - 1;
        unsigned short* dst = (which == 0) ? Qh : Kh;
        for (int rt = 0; rt < 4; ++rt)
            for (int ct = 0; ct < 4; ++ct)
                for (int i = 0; i < 4; ++i) {
                    int m = m0 + wr + rt * 16 + lrow4 + i;
                    int n = n0 + wc + ct * 16 + lcol;
                    float v = acc[rt][ct][i] + bias[n];
                    int b = m >> lsh, s = m & Lm1;
                    int h = n >> 6, d = n & 63;
                    dst[((size_t)((b * H_ + h) << lsh) + (size_t)s) * DH + d] = f2bf(v);
                }
    } else {
        for (int rt = 0; rt < 4; ++rt)
            for (int ct = 0; ct < 4; ++ct)
                for (int i = 0; i < 4; ++i) {
                    int rl2 = wr + rt * 16 + lrow4 + i;  // tile row (seq)
                    int cl  = wc + ct * 16 + lcol;       // tile col (h*64+d)
                    float v = acc[rt][ct][i] + bias[n0 + cl];
                    Cs[cl * 136 + rl2] = (short)f2bf(v);
                }
        __syncthreads();
        int b = m0 >> 11, r0 = m0 & 2047;
        int c = tid >> 1, half = tid & 1;
        int n = n0 + c, h = n >> 6, d = n & 63;
        unsigned short* dstp = VT + ((size_t)(b * H_ + h) * DH + d) * LK + r0 + half * 64;
        for (int j = 0; j < 8; ++j) {
            uint4_ v = *(const uint4_*)(&Cs[c * 136 + half * 64 + j * 8]);
            *(uint4_*)(dstp + j * 8) = v;
        }
    }
}

// ---------------------------------------------------------------------------
// Flash attention with relative_key_query pe terms.
// Round-17 (wave-density attack): 512-thread blocks, 8 waves, TWO 64-row
// Q-tiles per block (tile = wave>>2, wv = wave&3) sharing K/V tiles and
// barriers. Grid 512 = exactly 2 blocks/CU = ONE uniform resident batch
// (16 waves/CU, 4 waves/SIMD -- vs 2/SIMD in rounds 0-7, which left the
// VALU/DS/MFMA phases serialized with no cross-wave co-issue; proven by
// rounds 1/4/5/7: removing ops from any single pipe never moved the time).
//  - K double-buffered (staged via gll at iter top, drained at D(it), used
//    next iter); V SINGLE-buffered: V(it) issued at iter top, drained at D,
//    consumed at PV after D -- QK+G phase covers its latency. Saves 8 KB.
//  - Per-tile Gqk (65-dword rows, round-4-proven scatter) + per-tile Ps
//    (72-short rows). Per-wave dataflow identical to round-7 (VGPR ~124).
// LDS 76,288 B; launch_bounds(512,2).
// Tripwire: VGPR > 128 -> 1 block/CU -> flat ~295 (clamp next round).
// ---------------------------------------------------------------------------
__global__ __launch_bounds__(512, 2) void attn_kernel(
    const unsigned short* __restrict__ Qh, const unsigned short* __restrict__ Kh,
    const unsigned short* __restrict__ VT, const unsigned short* __restrict__ Eb,
    const float* __restrict__ mask, float* __restrict__ out)
{
    __shared__ short smem[38144];        // 76,288 B -> 2 blocks/CU
    // K0 @0 (4096), K1 @4096, V @8192 (4096); Q prologue borrows [0,8192)
    short* Gs = smem + 12288;            // u16 view of Gqk, 2 tiles x 8320
    unsigned int* Gqk = (unsigned int*)(smem + 12288);  // 2 x 64 x 65 dwords
    short* Ps = smem + 28928;            // 2 tiles x 64 x 72

    int bid = blockIdx.x;
    int l0base = (bid & 7) * 128;        // L2-local mapping
    int bh = bid >> 3;
    int b  = bh >> 4, h = bh & 15;
    int tid = threadIdx.x, wave = tid >> 6, lane = tid & 63;
    int wv = wave & 3, tile = wave >> 2;
    int l0 = l0base + tile * 64;
    int lr = lane & 15, lk8 = (lane >> 4) * 8, lr4 = (lane >> 4) * 4;
    int rl8 = lane >> 3;                          // staging row-in-group
    int sch = ((lane & 7) ^ rl8) << 3;            // pre-swizzled source chunk
    int co0 = ((lane >> 4) ^ (lr & 7)) << 3;      // swizzled frag-read offset

    unsigned int* Gq_t = Gqk + tile * 4160;
    short* Gs_t = Gs + tile * 8320;
    short* Ps_t = Ps + tile * 4608;

    const unsigned short* Kbase = Kh + (size_t)bh * LK * DH;
    const unsigned short* Vbase = VT + (size_t)bh * DH * LK;

    // ---- Prologue: 128 Q rows via gll into [0,8192), frags to regs. ----
    #pragma unroll
    for (int c = 0; c < 2; ++c) {
        int rw = wave * 16 + c * 8;               // wave-uniform row base
        GLOAD_LDS16(Qh + ((size_t)(bh * LQ + l0base + rw + rl8)) * DH + sch,
                    &smem[rw * 64]);
    }
    __syncthreads();                              // Q staged (vmcnt drained)
    short8 aq0 = *(const short8*)(&smem[(wave * 16 + lr) * 64 + co0]);
    short8 aq1 = *(const short8*)(&smem[(wave * 16 + lr) * 64 + (co0 ^ 32)]);
    __syncthreads();                              // frag reads done

    auto stage_K = [&](int nit, int buf) {
        short* Kb = smem + buf * 4096;
        int rw = wave * 8;                        // 8 waves cover rows 0..63
        GLOAD_LDS16(Kbase + (size_t)(nit * 64 + rw + rl8) * DH + sch, &Kb[rw * 64]);
    };
    auto stage_V = [&](int nit) {
        short* Vb = smem + 8192;
        int rw = wave * 8;
        GLOAD_LDS16(Vbase + (size_t)(rw + rl8) * LK + nit * 64 + sch, &Vb[rw * 64]);
    };
    stage_K(0, 0);

    float m_i[4], l_i[4];
    float4_ Oacc[4];
    for (int i = 0; i < 4; ++i) { m_i[i] = -1e30f; l_i[i] = 0.f; Oacc[i] = (float4_)0.f; }

    // E fragment register cache (per wave, keyed to its own l0): tile t of
    // the current window lives in ef[t ^ 4*(it&1)].
    short8 ef[8][2];
    {
        const unsigned short* ep = Eb + (size_t)(l0 + 1984 + lr) * DH + lk8;
        #pragma unroll
        for (int t = 0; t < 8; ++t) {
            ef[t][0] = *(const short8*)(ep + (size_t)t * 16 * DH);
            ef[t][1] = *(const short8*)(ep + (size_t)t * 16 * DH + 32);
        }
    }
    __syncthreads();                              // K(0) staged (vmcnt drained)

    for (int it2 = 0; it2 < 32; it2 += 2) {
      #pragma unroll
      for (int sub = 0; sub < 2; ++sub) {
        const int it = it2 + sub;
        const int p4 = sub * 4;                   // compile-time slot rotation
        int r0 = it * 64;
        const short* Kb = smem + sub * 4096;      // cur = it & 1
        const short* Vb = smem + 8192;

        if (it < 31) stage_K(it + 1, sub ^ 1);    // async; drained at (D)
        stage_V(it);                              // async; drained at (D);
                                                  // V buf free since END(it-1)

        // S = Q K^T ; capture the wave's own K frag for the Gk A-operand
        short8 ak0, ak1;
        float4_ Sacc[4];
        #pragma unroll
        for (int c = 0; c < 4; ++c) {
            short8 b0 = *(const short8*)(&Kb[(c * 16 + lr) * 64 + co0]);
            short8 b1 = *(const short8*)(&Kb[(c * 16 + lr) * 64 + (co0 ^ 32)]);
            float4_ s = (float4_)0.f;
            s = MFMA(aq0, b0, s);
            s = MFMA(aq1, b1, s);
            Sacc[c] = s;
            if (c == 0 || c == wv) { ak0 = b0; ak1 = b1; }
        }

        // G terms from register-cached E frags (union of Gq tiles wv..wv+4
        // and Gk tiles 3-wv..7-wv); scatter into per-tile Gqk dword slots:
        // Gq -> low u16 of (row, tr); Gk -> high u16 of (tl, row).
        #pragma unroll
        for (int t = 0; t < 8; ++t) {
            int dq = t - wv, dk = t - 3 + wv;
            bool needq = (unsigned)dq < 5u, needk = (unsigned)dk < 5u;
            if (!(needq || needk)) continue;
            short8 e0 = ef[t ^ p4][0], e1 = ef[t ^ p4][1];
            int u = t * 16 + lr;
            if (needq) {
                float4_ g = (float4_)0.f;
                g = MFMA(aq0, e0, g); g = MFMA(aq1, e1, g);
                unsigned int p0 = pack2(g[0], g[1]), p1 = pack2(g[2], g[3]);
                #pragma unroll
                for (int i = 0; i < 4; ++i) {
                    int row = wv * 16 + lr4 + i;         // q-row
                    unsigned int w32 = (i >> 1) ? p1 : p0;
                    unsigned short vq = (unsigned short)((i & 1) ? (w32 >> 16) : (w32 & 0xffff));
                    int tr = row - u + 63;               // score column
                    if ((unsigned)tr < 64u)
                        Gs_t[(row * 65 + tr) * 2] = (short)vq;
                }
            }
            if (needk) {
                float4_ gg = (float4_)0.f;
                gg = MFMA(ak0, e0, gg); gg = MFMA(ak1, e1, gg);
                unsigned int q0 = pack2(gg[0], gg[1]), q1 = pack2(gg[2], gg[3]);
                #pragma unroll
                for (int i = 0; i < 4; ++i) {
                    int row = wv * 16 + lr4 + i;         // k-row (score column)
                    unsigned int w32 = (i >> 1) ? q1 : q0;
                    unsigned short vk = (unsigned short)((i & 1) ? (w32 >> 16) : (w32 & 0xffff));
                    int tl = u + row - 63;               // score row
                    if ((unsigned)tl < 64u)
                        Gs_t[(tl * 65 + row) * 2 + 1] = (short)vk;
                }
            }
        }
        __syncthreads();   // (D) scatter visible; drains K(it+1) + V(it)

        // E prefetch for it+1: 4 new low tiles into the slots just freed.
        if (it < 31) {
            const unsigned short* ep =
                Eb + (size_t)(l0 + 1984 - 64 * (it + 1) + lr) * DH + lk8;
            #pragma unroll
            for (int t = 0; t < 4; ++t) {
                ef[t ^ p4 ^ 4][0] = *(const short8*)(ep + (size_t)t * 16 * DH);
                ef[t ^ p4 ^ 4][1] = *(const short8*)(ep + (size_t)t * 16 * DH + 32);
            }
        }

        // Softmax rows + P write (DPP reductions; per-tile Ps).
        float mk[4];
        for (int c = 0; c < 4; ++c) mk[c] = mask[b * LK + r0 + c * 16 + lr];
        #pragma unroll
        for (int i = 0; i < 4; ++i) {
            int tl = wv * 16 + lr4 + i;
            const unsigned int* gr = Gq_t + tl * 65 + lr;
            unsigned int gva[4];
            gva[0] = gr[0]; gva[1] = gr[16]; gva[2] = gr[32]; gva[3] = gr[48];
            float scv[4], mx = -1e30f;
            #pragma unroll
            for (int c = 0; c < 4; ++c) {
                float sq = bf2f((unsigned short)(gva[c] & 0xffff));
                float sk = bf2f((unsigned short)(gva[c] >> 16));
                float sc = (Sacc[c][i] + sq + sk) * 0.125f + mk[c];
                scv[c] = sc;
                mx = fmaxf(mx, sc);
            }
            mx = fmaxf(mx, dppmv<0xB1>(mx));    // xor1
            mx = fmaxf(mx, dppmv<0x4E>(mx));    // xor2
            mx = fmaxf(mx, dppmv<0x141>(mx));   // row_half_mirror
            mx = fmaxf(mx, dppmv<0x140>(mx));   // row_mirror
            float mnew = fmaxf(m_i[i], mx);
            float alpha = __expf(m_i[i] - mnew);
            m_i[i] = mnew;
            float e0 = __expf(scv[0] - mnew), e1 = __expf(scv[1] - mnew);
            float e2 = __expf(scv[2] - mnew), e3 = __expf(scv[3] - mnew);
            unsigned int p01 = pack2(e0, e1), p23 = pack2(e2, e3);
            float rs = bf2f((unsigned short)(p01 & 0xffff)) + bf2f((unsigned short)(p01 >> 16))
                     + bf2f((unsigned short)(p23 & 0xffff)) + bf2f((unsigned short)(p23 >> 16));
            rs += dppmv<0xB1>(rs);
            rs += dppmv<0x4E>(rs);
            rs += dppmv<0x141>(rs);
            rs += dppmv<0x140>(rs);
            l_i[i] = l_i[i] * alpha + rs;
            for (int nt = 0; nt < 4; ++nt) Oacc[nt][i] *= alpha;
            short* Pr = Ps_t + tl * 72;
            Pr[ 0 + lr] = (short)(unsigned short)(p01 & 0xffff);
            Pr[16 + lr] = (short)(unsigned short)(p01 >> 16);
            Pr[32 + lr] = (short)(unsigned short)(p23 & 0xffff);
            Pr[48 + lr] = (short)(unsigned short)(p23 >> 16);
        }
        // P·V (P A-frags from own-wave rows; same-wave write->read, in-order)
        const short* Pa = Ps_t + (wv * 16 + lr) * 72;
        short8 ap0 = *(const short8*)(Pa + lk8);
        short8 ap1 = *(const short8*)(Pa + 32 + lk8);
        #pragma unroll
        for (int nt = 0; nt < 4; ++nt) {
            short8 v0 = *(const short8*)(&Vb[(nt * 16 + lr) * 64 + co0]);
            short8 v1 = *(const short8*)(&Vb[(nt * 16 + lr) * 64 + (co0 ^ 32)]);
            Oacc[nt] = MFMA(ap0, v0, Oacc[nt]);
            Oacc[nt] = MFMA(ap1, v1, Oacc[nt]);
        }
        __syncthreads();   // (END) V/K[cur]/Gqk/Ps readers done -> restage
      }
    }

    // Epilogue: out[b][l][h*64+d] = O / l_i   (fp32 output)
    for (int nt = 0; nt < 4; ++nt)
        for (int i = 0; i < 4; ++i) {
            int row = l0 + wv * 16 + lr4 + i;
            int col = h * 64 + nt * 16 + lr;
            out[(size_t)(b * LQ + row) * D_ + col] = Oacc[nt][i] / l_i[i];
        }
}

extern "C" void kernel_launch(void* const* d_in, const int* in_sizes, int n_in,
                              void* d_out, int out_size, void* d_ws, size_t ws_size,
                              hipStream_t stream) {
    (void)in_sizes; (void)n_in; (void)out_size; (void)ws_size;
    const float* Xk   = (const float*)d_in[0]; // hidden_states [4,2048,1024] fp32
    const float* Xq   = (const float*)d_in[1]; // query_hidden  [4,1024,1024] fp32
    const float* mask = (const float*)d_in[2]; // [4,1,1,2048] fp32
    const float* Wq   = (const float*)d_in[3];
    const float* bq   = (const float*)d_in[4];
    const float* Wk   = (const float*)d_in[5];
    const float* bk   = (const float*)d_in[6];
    const float* Wv   = (const float*)d_in[7];
    const float* bv   = (const float*)d_in[8];
    const float* Eg   = (const float*)d_in[9]; // dist_emb [4095,64] fp32

    // workspace layout (bf16 elems), ~57 MB; cXk uses d_out as scratch
    // (exactly 16 MB; attn fully overwrites d_out afterwards).
    unsigned short* Qh  = (unsigned short*)d_ws;              //  4,194,304
    unsigned short* Kh  = Qh  + (size_t)4194304;              //  8,388,608
    unsigned short* VT  = Kh  + (size_t)8388608;              //  8,388,608
    unsigned short* cWq = VT  + (size_t)8388608;              //  1,048,576
    unsigned short* cWk = cWq + (size_t)1048576;              //  1,048,576
    unsigned short* cWv = cWk + (size_t)1048576;              //  1,048,576
    unsigned short* cEb = cWv + (size_t)1048576;              //    262,144 (pad)
    unsigned short* cXq = cEb + (size_t)262144;               //  4,194,304
    unsigned short* cXk = (unsigned short*)d_out;             //  8,388,608 (scratch)
    float* o = (float*)d_out;

    conv_kernel<<<7808, 256, 0, stream>>>(Wq, Wk, Wv, Eg, Xq, Xk,
                                          cWq, cWk, cWv, cEb, cXq, cXk);
    proj_kernel<<<1280, 256, 0, stream>>>(cXq, cXk, cWq, bq, cWk, bk, cWv, bv, Qh, Kh, VT);
    attn_kernel<<<512, 512, 0, stream>>>(Qh, Kh, VT, cEb, mask, o);
}

// Round 9
// 423.890 us; speedup vs baseline: 1.1616x; 1.1616x over previous
//
#include <hip/hip_runtime.h>
#include <hip/hip_bf16.h>

#define B_   4
#define H_   16
#define LQ   1024
#define LK   2048
#define D_   1024
#define DH   64

typedef __attribute__((ext_vector_type(8))) short  short8;
typedef __attribute__((ext_vector_type(4))) float  float4_;
typedef __attribute__((ext_vector_type(4))) unsigned int uint4_;

static __device__ __forceinline__ float bf2f(unsigned short u) {
    unsigned int x = ((unsigned int)u) << 16;
    return __builtin_bit_cast(float, x);
}
static __device__ __forceinline__ unsigned short f2bf(float f) {
    unsigned int x = __builtin_bit_cast(unsigned int, f);
    unsigned int lsb = (x >> 16) & 1u;
    x += 0x7fffu + lsb;
    return (unsigned short)(x >> 16);
}
// packed RNE fp32x2 -> bf16x2 (v_cvt_pk_bf16_f32 on gfx950)
static __device__ __forceinline__ unsigned int pack2(float a, float b) {
    __hip_bfloat162 h = __float22bfloat162_rn(make_float2(a, b));
    unsigned int r;
    __builtin_memcpy(&r, &h, 4);
    return r;
}

#define MFMA(a, b, c) __builtin_amdgcn_mfma_f32_16x16x32_bf16((a), (b), (c), 0, 0, 0)

// async global->LDS, 16B per lane; LDS dest is wave-uniform base + lane*16.
#define GLOAD_LDS16(g, l) __builtin_amdgcn_global_load_lds( \
    (const __attribute__((address_space(1))) unsigned int*)(const void*)(g), \
    (__attribute__((address_space(3))) unsigned int*)(void*)(l), 16, 0, 0)

// ---------------------------------------------------------------------------
// One-shot fp32 -> bf16 conversion: Wq/Wk/Wv, dist_emb, Xq/Xk.
// ---------------------------------------------------------------------------
__global__ __launch_bounds__(256) void conv_kernel(
    const float* __restrict__ Wq, const float* __restrict__ Wk,
    const float* __restrict__ Wv, const float* __restrict__ Eg,
    const float* __restrict__ Xq, const float* __restrict__ Xk,
    unsigned short* __restrict__ cWq, unsigned short* __restrict__ cWk,
    unsigned short* __restrict__ cWv, unsigned short* __restrict__ cEb,
    unsigned short* __restrict__ cXq, unsigned short* __restrict__ cXk)
{
    int bid = blockIdx.x;
    const float* src; unsigned short* dst; int nch;
    if (bid < 512)       { src = Wq; dst = cWq;              nch = 131072;  }
    else if (bid < 1024) { src = Wk; dst = cWk; bid -= 512;  nch = 131072;  }
    else if (bid < 1536) { src = Wv; dst = cWv; bid -= 1024; nch = 131072;  }
    else if (bid < 1664) { src = Eg; dst = cEb; bid -= 1536; nch = 32760;   }
    else if (bid < 3712) { src = Xq; dst = cXq; bid -= 1664; nch = 524288;  }
    else                 { src = Xk; dst = cXk; bid -= 3712; nch = 1048576; }
    int ch = bid * 256 + threadIdx.x;
    if (ch >= nch) return;
    const float* s = src + (size_t)ch * 8;
    float4_ v0 = *(const float4_*)s, v1 = *(const float4_*)(s + 4);
    uint4_ o;
    o[0] = pack2(v0[0], v0[1]); o[1] = pack2(v0[2], v0[3]);
    o[2] = pack2(v1[0], v1[1]); o[3] = pack2(v1[2], v1[3]);
    *(uint4_*)(dst + (size_t)ch * 8) = o;
}

// ---------------------------------------------------------------------------
// Projection GEMM (round-13 structure): pure-bf16 gll GEMM + LDS DOUBLE-BUFFER.
//  - Prologue stages buf0; each iter: stage(other buf) -> compute(cur) ->
//    ONE __syncthreads (drains vmcnt(0) + joins). Stage latency of tile k+1
//    is hidden under tile k's 32-MFMA compute phase.
//  - LDS linear [128][64] bf16 per operand per buffer (gll needs linear dest);
//    bank spread via XOR swizzle chunk' = chunk ^ (row&7) applied on the
//    GLOBAL source address (staging) and the read address (frags).
// which 0: Q -> Qh ; 1: K -> Kh ; 2: V -> VT (transposed via LDS).
// ---------------------------------------------------------------------------
__global__ __launch_bounds__(256) void proj_kernel(
    const unsigned short* __restrict__ Xq, const unsigned short* __restrict__ Xk,
    const unsigned short* __restrict__ Wq, const float* __restrict__ bq,
    const unsigned short* __restrict__ Wk, const float* __restrict__ bk,
    const unsigned short* __restrict__ Wv, const float* __restrict__ bv,
    unsigned short* __restrict__ Qh, unsigned short* __restrict__ Kh,
    unsigned short* __restrict__ VT)
{
    __shared__ short smem[32768];      // 65536 B -> 2 blocks/CU
    short* A0 = smem;                  // 128 x 64 bf16
    short* B0 = smem + 8192;
    short* A1 = smem + 16384;
    short* B1 = smem + 24576;
    short* Cs = smem;                  // 128 x 136 (V transpose, aliases)

    int bid = blockIdx.x;
    int which, tm, tn;
    const unsigned short *X; const float* bias; const unsigned short* W;
    if (bid < 256)      { which = 0; int t = bid;       tm = t >> 3; tn = t & 7; X = Xq; W = Wq; bias = bq; }
    else if (bid < 768) { which = 1; int t = bid - 256; tm = t >> 3; tn = t & 7; X = Xk; W = Wk; bias = bk; }
    else                { which = 2; int t = bid - 768; tm = t >> 3; tn = t & 7; X = Xk; W = Wv; bias = bv; }

    int tid  = threadIdx.x;
    int wave = tid >> 6, lane = tid & 63;
    int wr = (wave >> 1) * 64, wc = (wave & 1) * 64;
    int m0 = tm * 128, n0 = tn * 128;

    float4_ acc[4][4];
    for (int a = 0; a < 4; ++a) for (int c = 0; c < 4; ++c) acc[a][c] = (float4_)0.0f;

    // staging source: lane l of call c covers row = wave*32 + c*8 + (l>>3),
    // global chunk = (l&7) ^ (l>>3)  (so LDS[row][c'] = global chunk c'^(row&7))
    int rl = lane >> 3;
    int chs = (lane & 7) ^ rl;
    const unsigned short* Asrc = X + (size_t)(m0 + wave * 32 + rl) * D_ + (chs << 3);
    const unsigned short* Bsrc = W + (size_t)(n0 + wave * 32 + rl) * D_ + (chs << 3);

    int lrow = lane & 15, lk8 = (lane >> 4) * 8;
    int swz = lane & 7;                 // == row&7 for all frag-read rows

    auto stage = [&](short* Ad, short* Bd, int kt) {
        int k0 = kt * 64;
        #pragma unroll
        for (int c = 0; c < 4; ++c) {
            GLOAD_LDS16(Asrc + (size_t)(c * 8) * D_ + k0, &Ad[(wave * 32 + c * 8) * 64]);
            GLOAD_LDS16(Bsrc + (size_t)(c * 8) * D_ + k0, &Bd[(wave * 32 + c * 8) * 64]);
        }
    };
    auto compute = [&](const short* Aa, const short* Bb) {
        #pragma unroll
        for (int kk = 0; kk < 64; kk += 32) {
            int cgrp = (kk + lk8) >> 3;             // logical 16B chunk
            int coff = ((cgrp ^ swz) << 3);         // swizzled elem offset
            short8 af[4], bfr[4];
            #pragma unroll
            for (int rt = 0; rt < 4; ++rt)
                af[rt]  = *(const short8*)(&Aa[(wr + rt * 16 + lrow) * 64 + coff]);
            #pragma unroll
            for (int ct = 0; ct < 4; ++ct)
                bfr[ct] = *(const short8*)(&Bb[(wc + ct * 16 + lrow) * 64 + coff]);
            #pragma unroll
            for (int rt = 0; rt < 4; ++rt)
                #pragma unroll
                for (int ct = 0; ct < 4; ++ct)
                    acc[rt][ct] = MFMA(af[rt], bfr[ct], acc[rt][ct]);
        }
    };

    stage(A0, B0, 0);
    __syncthreads();                   // buf0 staged (vmcnt drained by barrier)
    for (int kt = 0; kt < 16; kt += 2) {
        if (kt + 1 < 16) stage(A1, B1, kt + 1);   // loads fly during compute
        compute(A0, B0);
        __syncthreads();               // kt+1 staged; A0/B0 readers done
        if (kt + 2 < 16) stage(A0, B0, kt + 2);
        compute(A1, B1);
        __syncthreads();               // kt+2 staged; A1/B1 readers done
    }
    // last barrier above also protects the Cs alias below.

    int lrow4 = (lane >> 4) * 4, lcol = lane & 15;
    if (which < 2) {
        int lsh = (which == 0) ? 10 : 11;          // LQ=1024, LK=2048
        int Lm1 = (1 << lsh) - 1;
        unsigned short* dst = (which == 0) ? Qh : Kh;
        for (int rt = 0; rt < 4; ++rt)
            for (int ct = 0; ct < 4; ++ct)
                for (int i = 0; i < 4; ++i) {
                    int m = m0 + wr + rt * 16 + lrow4 + i;
                    int n = n0 + wc + ct * 16 + lcol;
                    float v = acc[rt][ct][i] + bias[n];
                    int b = m >> lsh, s = m & Lm1;
                    int h = n >> 6, d = n & 63;
                    dst[((size_t)((b * H_ + h) << lsh) + (size_t)s) * DH + d] = f2bf(v);
                }
    } else {
        for (int rt = 0; rt < 4; ++rt)
            for (int ct = 0; ct < 4; ++ct)
                for (int i = 0; i < 4; ++i) {
                    int rl2 = wr + rt * 16 + lrow4 + i;  // tile row (seq)
                    int cl  = wc + ct * 16 + lcol;       // tile col (h*64+d)
                    float v = acc[rt][ct][i] + bias[n0 + cl];
                    Cs[cl * 136 + rl2] = (short)f2bf(v);
                }
        __syncthreads();
        int b = m0 >> 11, r0 = m0 & 2047;
        int c = tid >> 1, half = tid & 1;
        int n = n0 + c, h = n >> 6, d = n & 63;
        unsigned short* dstp = VT + ((size_t)(b * H_ + h) * DH + d) * LK + r0 + half * 64;
        for (int j = 0; j < 8; ++j) {
            uint4_ v = *(const uint4_*)(&Cs[c * 136 + half * 64 + j * 8]);
            *(uint4_*)(dstp + j * 8) = v;
        }
    }
}

// ---------------------------------------------------------------------------
// Flash attention with relative_key_query pe terms.
// Round-13 (best measured: attn 290.5 us): round-0 structure with:
//  - Gqk[tl][j]: 64 x 65 DWORDS (odd stride). Gq writes low u16 of slot
//    (row, tr); Gk writes high u16 of slot (tl, row) -- different bytes, no
//    race. Both scatters <=2-way banks (free); gather ~free.
//  - P in its own 64 x 72 buffer (144 B rows: 16B-aligned b128 ap reads).
// LDS 62720 B -> 2 blocks/CU; launch_bounds(256,2) so VGPR stays ~108.
// ---------------------------------------------------------------------------
__global__ __launch_bounds__(256, 2) void attn_kernel(
    const unsigned short* __restrict__ Qh, const unsigned short* __restrict__ Kh,
    const unsigned short* __restrict__ VT, const unsigned short* __restrict__ Eb,
    const float* __restrict__ mask, float* __restrict__ out)
{
    __shared__ short smem[31360];        // 62720 B -> 2 blocks/CU
    short* Qs  = smem;                   // 64 x 72 (aliases Ks)
    short* Ks  = smem;                   // 64 x 72
    short* VTs = smem + 4608;            // 64 x 72 (d-major)
    short* Es  = smem + 9216;            // 128 x 72
    short* Ps  = smem + 18432;           // 64 x 72 (P tile)
    unsigned int* Gqk = (unsigned int*)(smem + 23040);  // 64 x 65 dwords
    short* Gs  = smem + 23040;           // u16 view of Gqk

    int bid = blockIdx.x;
    int l0 = (bid & 15) * 64;            // L2-local mapping (r4-proven)
    int bh = bid >> 4;
    int b  = bh >> 4, h = bh & 15;
    int tid = threadIdx.x, wave = tid >> 6, lane = tid & 63;
    int lr = lane & 15, lk8 = (lane >> 4) * 8, lr4 = (lane >> 4) * 4;

    // Stage Q tile, pull frags to registers; Qs memory is then released to Ks.
    for (int i = 0; i < 2; ++i) {
        int idx = tid + 256 * i, row = idx >> 3, g = (idx & 7) * 8;
        *(uint4_*)(&Qs[row * 72 + g]) =
            *(const uint4_*)(Qh + ((size_t)(bh * LQ + l0 + row)) * DH + g);
    }
    __syncthreads();
    short8 aq0 = *(const short8*)(&Qs[(wave * 16 + lr) * 72 + lk8]);
    short8 aq1 = *(const short8*)(&Qs[(wave * 16 + lr) * 72 + 32 + lk8]);

    float m_i[4], l_i[4];
    float4_ Oacc[4];
    for (int i = 0; i < 4; ++i) { m_i[i] = -1e30f; l_i[i] = 0.f; Oacc[i] = (float4_)0.f; }

    const unsigned short* Kbase = Kh + (size_t)bh * LK * DH;
    const unsigned short* Vbase = VT + (size_t)bh * DH * LK;

    int srow = tid >> 3;          // 0..31
    int sg   = (tid & 7) * 8;     // 0..56

    uint4_ kr0, kr1, vr0, vr1, er0, er1, er2, er3;
    auto load_tiles = [&](int it2) {
        int r0_ = it2 * 64, jb_ = l0 - r0_ + 1984;
        kr0 = *(const uint4_*)(Kbase + (size_t)(r0_ + srow) * DH + sg);
        kr1 = *(const uint4_*)(Kbase + (size_t)(r0_ + srow + 32) * DH + sg);
        vr0 = *(const uint4_*)(Vbase + (size_t)srow * LK + r0_ + sg);
        vr1 = *(const uint4_*)(Vbase + (size_t)(srow + 32) * LK + r0_ + sg);
        er0 = *(const uint4_*)(Eb + (size_t)(jb_ + srow) * DH + sg);
        er1 = *(const uint4_*)(Eb + (size_t)(jb_ + srow + 32) * DH + sg);
        er2 = *(const uint4_*)(Eb + (size_t)(jb_ + srow + 64) * DH + sg);
        er3 = *(const uint4_*)(Eb + (size_t)(jb_ + srow + 96) * DH + sg);
    };
    load_tiles(0);

    for (int it = 0; it < 32; ++it) {
        int r0 = it * 64;

        __syncthreads();   // (A) prior-iter readers done -> safe to restage
        *(uint4_*)(&Ks[srow * 72 + sg])         = kr0;
        *(uint4_*)(&Ks[(srow + 32) * 72 + sg])  = kr1;
        *(uint4_*)(&VTs[srow * 72 + sg])        = vr0;
        *(uint4_*)(&VTs[(srow + 32) * 72 + sg]) = vr1;
        *(uint4_*)(&Es[srow * 72 + sg])         = er0;
        *(uint4_*)(&Es[(srow + 32) * 72 + sg])  = er1;
        *(uint4_*)(&Es[(srow + 64) * 72 + sg])  = er2;
        *(uint4_*)(&Es[(srow + 96) * 72 + sg])  = er3;
        __syncthreads();   // (B) staging visible
        if (it < 31) load_tiles(it + 1);   // prefetch next tiles into regs

        // S = Q K^T
        float4_ Sacc[4];
        for (int c = 0; c < 4; ++c) {
            short8 b0 = *(const short8*)(&Ks[(c * 16 + lr) * 72 + lk8]);
            short8 b1 = *(const short8*)(&Ks[(c * 16 + lr) * 72 + 32 + lk8]);
            float4_ s = (float4_)0.f;
            s = MFMA(aq0, b0, s);
            s = MFMA(aq1, b1, s);
            Sacc[c] = s;
        }

        // Gq (u-tiles wave..wave+4), Gk (u-tiles 3-wave..7-wave); pack bf16.
        short8 ak0 = *(const short8*)(&Ks[(wave * 16 + lr) * 72 + lk8]);
        short8 ak1 = *(const short8*)(&Ks[(wave * 16 + lr) * 72 + 32 + lk8]);
        unsigned int gqp[5][2], gkp[5][2];
        for (int tt = 0; tt < 5; ++tt) {
            int tqi = wave + tt;
            short8 e0 = *(const short8*)(&Es[(tqi * 16 + lr) * 72 + lk8]);
            short8 e1 = *(const short8*)(&Es[(tqi * 16 + lr) * 72 + 32 + lk8]);
            float4_ g = (float4_)0.f;
            g = MFMA(aq0, e0, g); g = MFMA(aq1, e1, g);
            gqp[tt][0] = pack2(g[0], g[1]); gqp[tt][1] = pack2(g[2], g[3]);
            int tk = (3 - wave) + tt;
            short8 f0 = *(const short8*)(&Es[(tk * 16 + lr) * 72 + lk8]);
            short8 f1 = *(const short8*)(&Es[(tk * 16 + lr) * 72 + 32 + lk8]);
            float4_ gg = (float4_)0.f;
            gg = MFMA(ak0, f0, gg); gg = MFMA(ak1, f1, gg);
            gkp[tt][0] = pack2(gg[0], gg[1]); gkp[tt][1] = pack2(gg[2], gg[3]);
        }

        // Scatter into Gqk dword slots: Gq -> low u16 of (row, tr);
        // Gk -> high u16 of (tl, row). Odd 65-dword stride: <=2-way banks.
        for (int tt = 0; tt < 5; ++tt) {
            int uq = (wave + tt) * 16 + lr;
            int uk = (3 - wave + tt) * 16 + lr;
            for (int i = 0; i < 4; ++i) {
                int row = wave * 16 + lr4 + i;           // Q-row for Gq, K-row for Gk
                unsigned int wq32 = gqp[tt][i >> 1], wk32 = gkp[tt][i >> 1];
                unsigned short vq = (unsigned short)((i & 1) ? (wq32 >> 16) : (wq32 & 0xffff));
                unsigned short vk = (unsigned short)((i & 1) ? (wk32 >> 16) : (wk32 & 0xffff));
                int tr = row - uq + 63;                  // score col for Gq
                if ((unsigned)tr < 64u)
                    Gs[(row * 65 + tr) * 2] = (short)vq;
                int tl = uk + row - 63;                  // score row for Gk
                if ((unsigned)tl < 64u)
                    Gs[(tl * 65 + row) * 2 + 1] = (short)vk;
            }
        }
        __syncthreads();   // (D) scatter visible

        // Softmax rows + P write (P in own buffer; same-wave row ownership).
        float mk[4];
        for (int c = 0; c < 4; ++c) mk[c] = mask[b * LK + r0 + c * 16 + lr];
        for (int i = 0; i < 4; ++i) {
            int tl = wave * 16 + lr4 + i;
            const unsigned int* gr = Gqk + tl * 65 + lr;
            unsigned int gva[4];
            gva[0] = gr[0]; gva[1] = gr[16]; gva[2] = gr[32]; gva[3] = gr[48];
            float scv[4], mx = -1e30f;
            #pragma unroll
            for (int c = 0; c < 4; ++c) {
                float sq = bf2f((unsigned short)(gva[c] & 0xffff));
                float sk = bf2f((unsigned short)(gva[c] >> 16));
                float sc = (Sacc[c][i] + sq + sk) * 0.125f + mk[c];
                scv[c] = sc;
                mx = fmaxf(mx, sc);
            }
            for (int off = 1; off < 16; off <<= 1) mx = fmaxf(mx, __shfl_xor(mx, off, 64));
            float mnew = fmaxf(m_i[i], mx);
            float alpha = __expf(m_i[i] - mnew);
            m_i[i] = mnew;
            float e0 = __expf(scv[0] - mnew), e1 = __expf(scv[1] - mnew);
            float e2 = __expf(scv[2] - mnew), e3 = __expf(scv[3] - mnew);
            unsigned int p01 = pack2(e0, e1), p23 = pack2(e2, e3);
            float rs = bf2f((unsigned short)(p01 & 0xffff)) + bf2f((unsigned short)(p01 >> 16))
                     + bf2f((unsigned short)(p23 & 0xffff)) + bf2f((unsigned short)(p23 >> 16));
            for (int off = 1; off < 16; off <<= 1) rs += __shfl_xor(rs, off, 64);
            l_i[i] = l_i[i] * alpha + rs;
            for (int nt = 0; nt < 4; ++nt) Oacc[nt][i] *= alpha;
            short* Pr = Ps + tl * 72;
            Pr[ 0 + lr] = (short)(unsigned short)(p01 & 0xffff);
            Pr[16 + lr] = (short)(unsigned short)(p01 >> 16);
            Pr[32 + lr] = (short)(unsigned short)(p23 & 0xffff);
            Pr[48 + lr] = (short)(unsigned short)(p23 >> 16);
        }
        // P·V (P A-frags from Ps rows; same-wave write->read, in-order)
        const short* Pa = Ps + (wave * 16 + lr) * 72;
        short8 ap0 = *(const short8*)(Pa + lk8);
        short8 ap1 = *(const short8*)(Pa + 32 + lk8);
        for (int nt = 0; nt < 4; ++nt) {
            short8 v0 = *(const short8*)(&VTs[(nt * 16 + lr) * 72 + lk8]);
            short8 v1 = *(const short8*)(&VTs[(nt * 16 + lr) * 72 + 32 + lk8]);
            Oacc[nt] = MFMA(ap0, v0, Oacc[nt]);
            Oacc[nt] = MFMA(ap1, v1, Oacc[nt]);
        }
    }

    // Epilogue: out[b][l][h*64+d] = O / l_i   (fp32 output)
    for (int nt = 0; nt < 4; ++nt)
        for (int i = 0; i < 4; ++i) {
            int row = l0 + wave * 16 + lr4 + i;
            int col = h * 64 + nt * 16 + lr;
            out[(size_t)(b * LQ + row) * D_ + col] = Oacc[nt][i] / l_i[i];
        }
}

extern "C" void kernel_launch(void* const* d_in, const int* in_sizes, int n_in,
                              void* d_out, int out_size, void* d_ws, size_t ws_size,
                              hipStream_t stream) {
    (void)in_sizes; (void)n_in; (void)out_size; (void)ws_size;
    const float* Xk   = (const float*)d_in[0]; // hidden_states [4,2048,1024] fp32
    const float* Xq   = (const float*)d_in[1]; // query_hidden  [4,1024,1024] fp32
    const float* mask = (const float*)d_in[2]; // [4,1,1,2048] fp32
    const float* Wq   = (const float*)d_in[3];
    const float* bq   = (const float*)d_in[4];
    const float* Wk   = (const float*)d_in[5];
    const float* bk   = (const float*)d_in[6];
    const float* Wv   = (const float*)d_in[7];
    const float* bv   = (const float*)d_in[8];
    const float* Eg   = (const float*)d_in[9]; // dist_emb [4095,64] fp32

    // workspace layout (bf16 elems), ~57 MB; cXk uses d_out as scratch
    // (exactly 16 MB; attn fully overwrites d_out afterwards).
    unsigned short* Qh  = (unsigned short*)d_ws;              //  4,194,304
    unsigned short* Kh  = Qh  + (size_t)4194304;              //  8,388,608
    unsigned short* VT  = Kh  + (size_t)8388608;              //  8,388,608
    unsigned short* cWq = VT  + (size_t)8388608;              //  1,048,576
    unsigned short* cWk = cWq + (size_t)1048576;              //  1,048,576
    unsigned short* cWv = cWk + (size_t)1048576;              //  1,048,576
    unsigned short* cEb = cWv + (size_t)1048576;              //    262,144 (pad)
    unsigned short* cXq = cEb + (size_t)262144;               //  4,194,304
    unsigned short* cXk = (unsigned short*)d_out;             //  8,388,608 (scratch)
    float* o = (float*)d_out;

    conv_kernel<<<7808, 256, 0, stream>>>(Wq, Wk, Wv, Eg, Xq, Xk,
                                          cWq, cWk, cWv, cEb, cXq, cXk);
    proj_kernel<<<1280, 256, 0, stream>>>(cXq, cXk, cWq, bq, cWk, bk, cWv, bv, Qh, Kh, VT);
    attn_kernel<<<1024, 256, 0, stream>>>(Qh, Kh, VT, cEb, mask, o);
}